// Round 8
// baseline (649.305 us; speedup 1.0000x reference)
//
#include <hip/hip_runtime.h>
#include <math.h>

#define HDIM 2048
#define OUTN 32000
#define KOUT 3072
#define NPART 2000   // logits blocks == (m,s) partial pairs

__device__ __forceinline__ float wave_reduce_sum(float v) {
    #pragma unroll
    for (int off = 32; off > 0; off >>= 1)
        v += __shfl_down(v, off, 64);
    return v;
}

__device__ __forceinline__ float dot4(float4 a, float4 b) {
    return a.x * b.x + a.y * b.y + a.z * b.z + a.w * b.w;
}

// Non-temporal float4 load: weights are streamed exactly once per invocation;
// 'nt' keeps the 661 MB stream from evicting the reused broadcast vectors.
// __builtin_nontemporal_load requires a native clang vector type, not
// HIP_vector_type — route through ext_vector_type(4) (bit-identical layout).
typedef float nfloat4 __attribute__((ext_vector_type(4)));
__device__ __forceinline__ float4 ldnt4(const float4* p) {
    nfloat4 v = __builtin_nontemporal_load((const nfloat4*)p);
    return make_float4(v.x, v.y, v.z, v.w);
}

__device__ __forceinline__ float sigmoidf_(float x) {
    return 1.0f / (1.0f + __expf(-x));
}

// One LSTM layer, batch=1. Grid: 1024 blocks x 256 threads.
// Block b owns hidden units n0=2b, n0+1. Wave w computes gate rows
// (n0 + w*HDIM) and (n0+1 + w*HDIM): w0=i, w1=f, w2=g, w3=o.
// Two units per wave amortizes the broadcast x/h loads over 2 weight rows.
__global__ __launch_bounds__(256) void lstm_kernel(
    const float* __restrict__ xa,    // x[0:1024]
    const float* __restrict__ xb,    // x[1024:2048]
    const float* __restrict__ h,     // [2048]
    const float* __restrict__ c,     // [2048]
    const float* __restrict__ w_ih,  // [8192, 2048] row-major
    const float* __restrict__ w_hh,  // [8192, 2048]
    const float* __restrict__ b_ih,  // [8192]
    const float* __restrict__ b_hh,  // [8192]
    float* __restrict__ h_out,       // [2048]
    float* __restrict__ c_out)       // [2048]
{
    const int wave = threadIdx.x >> 6;
    const int lane = threadIdx.x & 63;
    const int n0   = blockIdx.x * 2;
    const int row0 = n0 + wave * HDIM;   // second row is row0+1

    const float4* wi0 = (const float4*)(w_ih + (size_t)row0 * HDIM);
    const float4* wh0 = (const float4*)(w_hh + (size_t)row0 * HDIM);
    const float4* xa4 = (const float4*)xa;   // 256 float4
    const float4* xb4 = (const float4*)xb;   // 256 float4
    const float4* h4  = (const float4*)h;    // 512 float4

    float a0 = 0.f, a1 = 0.f;
    #pragma unroll
    for (int it = 0; it < 8; ++it) {
        const int k4 = it * 64 + lane;                  // float4 index in row
        float4 xv = (it < 4) ? xa4[k4] : xb4[k4 - 256]; // compile-time select
        float4 hv = h4[k4];
        a0 += dot4(ldnt4(&wi0[k4]),       xv) + dot4(ldnt4(&wh0[k4]),       hv);
        a1 += dot4(ldnt4(&wi0[k4 + 512]), xv) + dot4(ldnt4(&wh0[k4 + 512]), hv);
    }
    a0 = wave_reduce_sum(a0);
    a1 = wave_reduce_sum(a1);

    __shared__ float sg[4][2];
    if (lane == 0) {
        sg[wave][0] = a0 + b_ih[row0]     + b_hh[row0];
        sg[wave][1] = a1 + b_ih[row0 + 1] + b_hh[row0 + 1];
    }
    __syncthreads();

    if (threadIdx.x < 2) {
        const int t  = threadIdx.x;      // unit selector
        float gi = sigmoidf_(sg[0][t]);
        float gf = sigmoidf_(sg[1][t]);
        float gg = tanhf(sg[2][t]);
        float go = sigmoidf_(sg[3][t]);
        float cn = gf * c[n0 + t] + gi * gg;
        float hn = go * tanhf(cn);
        c_out[n0 + t] = cn;
        h_out[n0 + t] = hn;
    }
}

// logits[row] = dot(w_out[row,:], concat(category, h2)) + b_out[row]
// Grid: 2000 blocks x 256 threads. Block b: rows b*16 + wave*4 + {0..3}.
// 4 rows per wave amortizes the broadcast concat-vector load 4x and gives
// each wave 4 independent weight streams. Also emits the block's
// online-softmax partial (max, sumexp) so the LSE pass shrinks 32000->2000.
__global__ __launch_bounds__(256) void logits_kernel(
    const float* __restrict__ cat,     // [1024]
    const float* __restrict__ h2,      // [2048]
    const float* __restrict__ w_out,   // [32000, 3072]
    const float* __restrict__ b_out,   // [32000]
    float* __restrict__ logits,        // [32000]
    float2* __restrict__ partial)      // [2000] (m, s) per block
{
    const int wave = threadIdx.x >> 6;
    const int lane = threadIdx.x & 63;
    const int row0 = blockIdx.x * 16 + wave * 4;

    const float4* w4 = (const float4*)(w_out + (size_t)row0 * KOUT);
    const float4* c4 = (const float4*)cat;  // 256 float4
    const float4* h4 = (const float4*)h2;   // 512 float4

    float a0 = 0.f, a1 = 0.f, a2 = 0.f, a3 = 0.f;
    #pragma unroll
    for (int it = 0; it < 12; ++it) {
        const int k4 = it * 64 + lane;
        float4 v = (it < 4) ? c4[k4] : h4[k4 - 256];
        a0 += dot4(ldnt4(&w4[k4]),        v);   // row stride = KOUT/4 = 768 f4
        a1 += dot4(ldnt4(&w4[k4 + 768]),  v);
        a2 += dot4(ldnt4(&w4[k4 + 1536]), v);
        a3 += dot4(ldnt4(&w4[k4 + 2304]), v);
    }
    a0 = wave_reduce_sum(a0);
    a1 = wave_reduce_sum(a1);
    a2 = wave_reduce_sum(a2);
    a3 = wave_reduce_sum(a3);

    __shared__ float sm[4], ss[4];
    if (lane == 0) {
        a0 += b_out[row0];
        a1 += b_out[row0 + 1];
        a2 += b_out[row0 + 2];
        a3 += b_out[row0 + 3];
        *(float4*)(logits + row0) = make_float4(a0, a1, a2, a3); // row0 % 4 == 0
        float m = fmaxf(fmaxf(a0, a1), fmaxf(a2, a3));
        float s = __expf(a0 - m) + __expf(a1 - m) + __expf(a2 - m) + __expf(a3 - m);
        sm[wave] = m; ss[wave] = s;
    }
    __syncthreads();
    if (threadIdx.x == 0) {
        float M = sm[0], S = ss[0];
        #pragma unroll
        for (int w = 1; w < 4; ++w) {
            float mn = fmaxf(M, sm[w]);
            S = S * __expf(M - mn) + ss[w] * __expf(sm[w] - mn);
            M = mn;
        }
        partial[blockIdx.x] = make_float2(M, S);
    }
}

// Combine 2000 (m, s) partials -> *logz = M + log(S). Single block.
// Every thread gets >=1 pair (2000 >= 1024) so all lane maxes are finite
// before the shuffle merge (avoids -inf - -inf = NaN).
__global__ __launch_bounds__(1024) void lse_combine(
    const float2* __restrict__ partial, float* __restrict__ logz)
{
    float m = -INFINITY, s = 0.f;
    for (int i = threadIdx.x; i < NPART; i += 1024) {
        float2 p  = partial[i];
        float  mn = fmaxf(m, p.x);
        s = s * __expf(m - mn) + p.y * __expf(p.x - mn); // first iter: 0*exp(-inf)=0
        m = mn;
    }
    #pragma unroll
    for (int off = 32; off > 0; off >>= 1) {
        float m2 = __shfl_down(m, off, 64);
        float s2 = __shfl_down(s, off, 64);
        float mn = fmaxf(m, m2);
        s = s * __expf(m - mn) + s2 * __expf(m2 - mn);
        m = mn;
    }
    __shared__ float smm[16], sss[16];
    const int wave = threadIdx.x >> 6;
    const int lane = threadIdx.x & 63;
    if (lane == 0) { smm[wave] = m; sss[wave] = s; }
    __syncthreads();
    if (threadIdx.x == 0) {
        float M = smm[0], S = sss[0];
        for (int w = 1; w < 16; ++w) {
            float mn = fmaxf(M, smm[w]);
            S = S * __expf(M - mn) + sss[w] * __expf(smm[w] - mn);
            M = mn;
        }
        *logz = M + logf(S);
    }
}

// logp[i] = logits[i] - logZ.  Grid: 125 x 256 == 32000 exactly.
__global__ __launch_bounds__(256) void sub_kernel(
    const float* __restrict__ logits, const float* __restrict__ logz,
    float* __restrict__ out)
{
    const int i = blockIdx.x * 256 + threadIdx.x;
    out[i] = logits[i] - *logz;
}

extern "C" void kernel_launch(void* const* d_in, const int* in_sizes, int n_in,
                              void* d_out, int out_size, void* d_ws, size_t ws_size,
                              hipStream_t stream) {
    const float* category = (const float*)d_in[0];   // [1024]
    const float* input    = (const float*)d_in[1];   // [1024]
    const float* hidden   = (const float*)d_in[2];   // [2,1,2048]
    const float* cell     = (const float*)d_in[3];   // [2,1,2048]
    const float* w_ih_l0  = (const float*)d_in[4];
    const float* w_hh_l0  = (const float*)d_in[5];
    const float* b_ih_l0  = (const float*)d_in[6];
    const float* b_hh_l0  = (const float*)d_in[7];
    const float* w_ih_l1  = (const float*)d_in[8];
    const float* w_hh_l1  = (const float*)d_in[9];
    const float* b_ih_l1  = (const float*)d_in[10];
    const float* b_hh_l1  = (const float*)d_in[11];
    const float* w_out    = (const float*)d_in[12];
    const float* b_out    = (const float*)d_in[13];

    float* out  = (float*)d_out;
    float* logp = out;                    // [32000]
    float* h1   = out + OUTN;             // new_hidden[0]
    float* h2   = out + OUTN + HDIM;      // new_hidden[1]
    float* c1   = out + OUTN + 2 * HDIM;  // new_cell[0]
    float* c2   = out + OUTN + 3 * HDIM;  // new_cell[1]

    float* logits = (float*)d_ws;         // [32000]
    float* logz   = logits + OUTN;        // [1]
    // Stage (m,s) partials in the logp output region: 2000*8B = 16 KB of the
    // 128 KB logp buffer; written by logits_kernel, consumed by lse_combine,
    // then fully overwritten by sub_kernel (kernel-boundary serialization on
    // the single stream makes this race-free). Avoids growing workspace use.
    float2* partial = (float2*)logp;

    // layer 0: x = concat(category, input)
    lstm_kernel<<<HDIM / 2, 256, 0, stream>>>(category, input,
                                              hidden, cell,
                                              w_ih_l0, w_hh_l0, b_ih_l0, b_hh_l0,
                                              h1, c1);
    // layer 1: x = h1 (contiguous; split into two halves for the shared kernel)
    lstm_kernel<<<HDIM / 2, 256, 0, stream>>>(h1, h1 + 1024,
                                              hidden + HDIM, cell + HDIM,
                                              w_ih_l1, w_hh_l1, b_ih_l1, b_hh_l1,
                                              h2, c2);
    logits_kernel<<<NPART, 256, 0, stream>>>(category, h2, w_out, b_out,
                                             logits, partial);
    lse_combine<<<1, 1024, 0, stream>>>(partial, logz);
    sub_kernel<<<OUTN / 256, 256, 0, stream>>>(logits, logz, logp);
}